// Round 1
// baseline (187.121 us; speedup 1.0000x reference)
//
#include <hip/hip_runtime.h>
#include <hip/hip_bf16.h>
#include <cstdint>
#include <cmath>

// Shapes (hard-coded to the reference): B=4, S=4096, D=1024, DK=DV=128.
// ws layout: Qb[16384][128]bf16 @0 (4MB) | Kb @4MB | Vt[B][128][4096]bf16 @8MB
//            | Wtq bf16[128][1024] @12MB | Wtk @12.25MB | Wtv @12.5MB  (13MB total)

typedef __bf16 bf16x8 __attribute__((ext_vector_type(8)));
typedef float f32x4 __attribute__((ext_vector_type(4)));

__device__ __forceinline__ unsigned short f2bf(float f) {
  unsigned u = __float_as_uint(f);
  u += 0x7fffu + ((u >> 16) & 1u);   // RNE
  return (unsigned short)(u >> 16);
}

__device__ __forceinline__ bf16x8 ld_frag(const char* p) {
  uint4 u = *reinterpret_cast<const uint4*>(p);
  return __builtin_bit_cast(bf16x8, u);
}

// ---------------- W transpose: [1024][128] f32 -> [128][1024] bf16 ----------
__global__ __launch_bounds__(256) void prep_wt_kernel(const float* __restrict__ W,
                                                      unsigned short* __restrict__ Wt) {
  __shared__ float tile[64][65];
  int kt = blockIdx.x, nt = blockIdx.y;   // (16, 2)
  int tid = threadIdx.x;
  int c = tid & 63;
  int r0 = (tid >> 6) * 16;
#pragma unroll
  for (int i = 0; i < 16; ++i) {
    int r = r0 + i;
    tile[r][c] = W[(size_t)(kt * 64 + r) * 128 + nt * 64 + c];
  }
  __syncthreads();
#pragma unroll
  for (int i = 0; i < 16; ++i) {
    int n = r0 + i;
    Wt[(size_t)(nt * 64 + n) * 1024 + kt * 64 + c] = f2bf(tile[c][n]);
  }
}

// ---------------- projections: X[16384][1024]f32 @ Wt -> bf16 outputs -------
__global__ __launch_bounds__(256) void proj_kernel(
    const float* __restrict__ qx, const float* __restrict__ kx, const float* __restrict__ vx,
    const unsigned short* __restrict__ Wtq, const unsigned short* __restrict__ Wtk,
    const unsigned short* __restrict__ Wtv,
    const float* __restrict__ bq, const float* __restrict__ bk, const float* __restrict__ bv,
    unsigned short* __restrict__ Qb, unsigned short* __restrict__ Kb,
    unsigned short* __restrict__ Vtb) {
  const int mode = blockIdx.y;  // 0=Q 1=K 2=V
  const float* x = (mode == 0) ? qx : (mode == 1) ? kx : vx;
  const unsigned short* Wt = (mode == 0) ? Wtq : (mode == 1) ? Wtk : Wtv;
  const float* bias = (mode == 0) ? bq : (mode == 1) ? bk : bv;

  __shared__ uint4 ldsA4[1024];  // 128 rows x 64 k bf16, swizzled
  __shared__ uint4 ldsW4[1024];  // 128 n-rows x 64 k bf16, swizzled
  char* ldsA = (char*)ldsA4;
  char* ldsW = (char*)ldsW4;

  const int tid = threadIdx.x;
  const int lane = tid & 63, wid = tid >> 6;
  const int l15 = lane & 15, hi = lane >> 4;
  const int wm = wid >> 1, wn = wid & 1;
  const long row0 = (long)blockIdx.x * 128;

  f32x4 acc[4][4];
#pragma unroll
  for (int i = 0; i < 4; ++i)
#pragma unroll
    for (int j = 0; j < 4; ++j) acc[i][j] = f32x4{0.f, 0.f, 0.f, 0.f};

  for (int kt = 0; kt < 16; ++kt) {
    const int k0 = kt * 64;
    // stage A (fp32 -> bf16)
#pragma unroll
    for (int i = 0; i < 4; ++i) {
      int u = tid + 256 * i;          // 1024 units of 8 elems
      int row = u >> 3, c8 = u & 7;
      const float* src = x + (row0 + row) * 1024 + k0 + c8 * 8;
      float4 f0 = *reinterpret_cast<const float4*>(src);
      float4 f1 = *reinterpret_cast<const float4*>(src + 4);
      uint4 w;
      w.x = (unsigned)f2bf(f0.x) | ((unsigned)f2bf(f0.y) << 16);
      w.y = (unsigned)f2bf(f0.z) | ((unsigned)f2bf(f0.w) << 16);
      w.z = (unsigned)f2bf(f1.x) | ((unsigned)f2bf(f1.y) << 16);
      w.w = (unsigned)f2bf(f1.z) | ((unsigned)f2bf(f1.w) << 16);
      int off = (row * 128 + c8 * 16) ^ ((row & 7) << 4);
      *reinterpret_cast<uint4*>(ldsA + off) = w;
      // stage Wt tile (already bf16)
      const unsigned short* wsrc = Wt + (size_t)row * 1024 + k0 + c8 * 8;
      uint4 wv = *reinterpret_cast<const uint4*>(wsrc);
      *reinterpret_cast<uint4*>(ldsW + off) = wv;
    }
    __syncthreads();
#pragma unroll
    for (int kk = 0; kk < 2; ++kk) {
      bf16x8 af[4], bfv[4];
#pragma unroll
      for (int mi = 0; mi < 4; ++mi) {
        int row = wm * 64 + mi * 16 + l15;
        af[mi] = ld_frag(ldsA + ((row * 128 + kk * 64 + hi * 16) ^ ((row & 7) << 4)));
      }
#pragma unroll
      for (int ni = 0; ni < 4; ++ni) {
        int row = wn * 64 + ni * 16 + l15;
        bfv[ni] = ld_frag(ldsW + ((row * 128 + kk * 64 + hi * 16) ^ ((row & 7) << 4)));
      }
#pragma unroll
      for (int mi = 0; mi < 4; ++mi)
#pragma unroll
        for (int ni = 0; ni < 4; ++ni)
          acc[mi][ni] = __builtin_amdgcn_mfma_f32_16x16x32_bf16(af[mi], bfv[ni], acc[mi][ni], 0, 0, 0);
    }
    __syncthreads();
  }

  // epilogue: +bias, (Q: * 1/sqrt(128)), store
#pragma unroll
  for (int ni = 0; ni < 4; ++ni) {
    int n = wn * 64 + ni * 16 + l15;
    float bv_ = bias[n];
#pragma unroll
    for (int mi = 0; mi < 4; ++mi) {
      long m = row0 + wm * 64 + mi * 16 + hi * 4;
      f32x4 a = acc[mi][ni];
      if (mode == 2) {
        int bb = (int)(m >> 12);
        int s = (int)(m & 4095);
        ushort4 pk;
        pk.x = f2bf(a.x + bv_); pk.y = f2bf(a.y + bv_);
        pk.z = f2bf(a.z + bv_); pk.w = f2bf(a.w + bv_);
        *reinterpret_cast<ushort4*>(Vtb + ((size_t)(bb * 128 + n)) * 4096 + s) = pk;
      } else {
        const float sc = (mode == 0) ? 0.08838834764831845f : 1.0f;
        unsigned short* outp = (mode == 0) ? Qb : Kb;
        outp[(m + 0) * 128 + n] = f2bf((a.x + bv_) * sc);
        outp[(m + 1) * 128 + n] = f2bf((a.y + bv_) * sc);
        outp[(m + 2) * 128 + n] = f2bf((a.z + bv_) * sc);
        outp[(m + 3) * 128 + n] = f2bf((a.w + bv_) * sc);
      }
    }
  }
}

// ---------------- flash attention ------------------------------------------
__global__ __launch_bounds__(256) void attn_kernel(
    const unsigned short* __restrict__ Qb, const unsigned short* __restrict__ Kb,
    const unsigned short* __restrict__ Vtb, float* __restrict__ out) {
  __shared__ uint4 ldsK4[1024];  // 64 kv-rows x 128 d bf16, swizzled
  __shared__ uint4 ldsV4[1024];  // 128 dv-rows x 64 k bf16, swizzled
  __shared__ uint4 ldsP4[512];   // per-wave 16 x 64 bf16, swizzled
  char* ldsK = (char*)ldsK4;
  char* ldsV = (char*)ldsV4;
  char* ldsP = (char*)ldsP4;

  const int tid = threadIdx.x;
  const int lane = tid & 63, wid = tid >> 6;
  const int l15 = lane & 15, hi = lane >> 4;
  const int b = blockIdx.y;
  const int q0 = blockIdx.x * 64 + wid * 16;
  const float L2E = 1.44269504088896f;

  // hoist Q fragments (A-operand: 16 rows x 128 d)
  bf16x8 qf[4];
  {
    const unsigned short* qp = Qb + ((size_t)(b * 4096) + q0 + l15) * 128 + hi * 8;
#pragma unroll
    for (int kd = 0; kd < 4; ++kd)
      qf[kd] = __builtin_bit_cast(bf16x8, *reinterpret_cast<const uint4*>(qp + kd * 32));
  }

  f32x4 oacc[8];
#pragma unroll
  for (int d = 0; d < 8; ++d) oacc[d] = f32x4{0.f, 0.f, 0.f, 0.f};
  float mrun[4], lrun[4];
#pragma unroll
  for (int r = 0; r < 4; ++r) { mrun[r] = -INFINITY; lrun[r] = 0.f; }

  char* pbase = ldsP + wid * 2048;

  for (int t = 0; t < 64; ++t) {
    const int kv0 = t * 64;
    // stage K tile [64][128] bf16
    const char* kg = (const char*)Kb + ((size_t)(b * 4096) + kv0) * 256;
#pragma unroll
    for (int i = 0; i < 4; ++i) {
      int u = tid + 256 * i;
      int row = u >> 4, c = u & 15;
      uint4 val = *reinterpret_cast<const uint4*>(kg + row * 256 + c * 16);
      *reinterpret_cast<uint4*>(ldsK + ((row * 256 + c * 16) ^ ((row & 7) << 4))) = val;
    }
    // stage Vt tile [128 dv][64 k] bf16
    const char* vg = (const char*)Vtb + (size_t)b * 128 * 4096 * 2 + (size_t)kv0 * 2;
#pragma unroll
    for (int i = 0; i < 4; ++i) {
      int u = tid + 256 * i;
      int dv = u >> 3, c = u & 7;
      uint4 val = *reinterpret_cast<const uint4*>(vg + (size_t)dv * 8192 + c * 16);
      *reinterpret_cast<uint4*>(ldsV + ((dv * 128 + c * 16) ^ ((dv & 7) << 4))) = val;
    }
    __syncthreads();

    // QK^T: sc[j0] holds D rows = q (hi*4+r), col = kv (j0*16 + l15)
    f32x4 sc[4];
#pragma unroll
    for (int j0 = 0; j0 < 4; ++j0) sc[j0] = f32x4{0.f, 0.f, 0.f, 0.f};
#pragma unroll
    for (int j0 = 0; j0 < 4; ++j0) {
      int row = j0 * 16 + l15;
#pragma unroll
      for (int kd = 0; kd < 4; ++kd) {
        bf16x8 kf = ld_frag(ldsK + ((row * 256 + kd * 64 + hi * 16) ^ ((row & 7) << 4)));
        sc[j0] = __builtin_amdgcn_mfma_f32_16x16x32_bf16(qf[kd], kf, sc[j0], 0, 0, 0);
      }
    }

    // online softmax (per q-row = (hi, r); reduce over 16 lanes & 4 j0)
    float mt[4];
#pragma unroll
    for (int r = 0; r < 4; ++r)
      mt[r] = fmaxf(fmaxf(sc[0][r], sc[1][r]), fmaxf(sc[2][r], sc[3][r]));
#pragma unroll
    for (int r = 0; r < 4; ++r) {
      mt[r] = fmaxf(mt[r], __shfl_xor(mt[r], 1));
      mt[r] = fmaxf(mt[r], __shfl_xor(mt[r], 2));
      mt[r] = fmaxf(mt[r], __shfl_xor(mt[r], 4));
      mt[r] = fmaxf(mt[r], __shfl_xor(mt[r], 8));
    }
    float mnew[4], scl[4], psum[4];
#pragma unroll
    for (int r = 0; r < 4; ++r) {
      mnew[r] = fmaxf(mrun[r], mt[r]);
      scl[r] = exp2f((mrun[r] - mnew[r]) * L2E);
      mrun[r] = mnew[r];
      psum[r] = 0.f;
    }
    // P = exp(sc - m), write bf16 to per-wave LDS in A-layout source form
#pragma unroll
    for (int j0 = 0; j0 < 4; ++j0) {
#pragma unroll
      for (int r = 0; r < 4; ++r) {
        float p = exp2f((sc[j0][r] - mnew[r]) * L2E);
        psum[r] += p;
        int row = hi * 4 + r;
        int off = (row * 128 + (j0 * 16 + l15) * 2) ^ ((row & 7) << 4);
        *reinterpret_cast<unsigned short*>(pbase + off) = f2bf(p);
      }
    }
#pragma unroll
    for (int r = 0; r < 4; ++r) {
      psum[r] += __shfl_xor(psum[r], 1);
      psum[r] += __shfl_xor(psum[r], 2);
      psum[r] += __shfl_xor(psum[r], 4);
      psum[r] += __shfl_xor(psum[r], 8);
      lrun[r] = lrun[r] * scl[r] + psum[r];
    }
    // rescale output accumulator
#pragma unroll
    for (int d = 0; d < 8; ++d) {
      oacc[d][0] *= scl[0]; oacc[d][1] *= scl[1];
      oacc[d][2] *= scl[2]; oacc[d][3] *= scl[3];
    }

    asm volatile("s_waitcnt lgkmcnt(0)" ::: "memory");  // P writes -> P reads (wave-local)

    // PV: A = P (16x64), B = V (64 x 128dv) from Vt rows
#pragma unroll
    for (int kk = 0; kk < 2; ++kk) {
      bf16x8 pf = ld_frag(pbase + ((l15 * 128 + kk * 64 + hi * 16) ^ ((l15 & 7) << 4)));
#pragma unroll
      for (int d = 0; d < 8; ++d) {
        int vrow = d * 16 + l15;
        bf16x8 vf = ld_frag(ldsV + ((vrow * 128 + kk * 64 + hi * 16) ^ ((vrow & 7) << 4)));
        oacc[d] = __builtin_amdgcn_mfma_f32_16x16x32_bf16(pf, vf, oacc[d], 0, 0, 0);
      }
    }
    __syncthreads();
  }

  // epilogue: normalize and store f32
  float inv[4];
#pragma unroll
  for (int r = 0; r < 4; ++r) inv[r] = 1.0f / lrun[r];
#pragma unroll
  for (int d = 0; d < 8; ++d) {
#pragma unroll
    for (int r = 0; r < 4; ++r) {
      out[((size_t)(b * 4096) + q0 + hi * 4 + r) * 128 + d * 16 + l15] = oacc[d][r] * inv[r];
    }
  }
}

extern "C" void kernel_launch(void* const* d_in, const int* in_sizes, int n_in,
                              void* d_out, int out_size, void* d_ws, size_t ws_size,
                              hipStream_t stream) {
  const float* q  = (const float*)d_in[0];
  const float* k  = (const float*)d_in[1];
  const float* v  = (const float*)d_in[2];
  const float* Wq = (const float*)d_in[3];
  const float* bq = (const float*)d_in[4];
  const float* Wk = (const float*)d_in[5];
  const float* bk = (const float*)d_in[6];
  const float* Wv = (const float*)d_in[7];
  const float* bv = (const float*)d_in[8];
  float* out = (float*)d_out;

  char* ws = (char*)d_ws;
  unsigned short* Qb  = (unsigned short*)(ws);
  unsigned short* Kb  = (unsigned short*)(ws + (4u << 20));
  unsigned short* Vtb = (unsigned short*)(ws + (8u << 20));
  unsigned short* Wtq = (unsigned short*)(ws + (12u << 20));
  unsigned short* Wtk = (unsigned short*)(ws + (12u << 20) + (256u << 10));
  unsigned short* Wtv = (unsigned short*)(ws + (12u << 20) + (512u << 10));

  prep_wt_kernel<<<dim3(16, 2), 256, 0, stream>>>(Wq, Wtq);
  prep_wt_kernel<<<dim3(16, 2), 256, 0, stream>>>(Wk, Wtk);
  prep_wt_kernel<<<dim3(16, 2), 256, 0, stream>>>(Wv, Wtv);
  proj_kernel<<<dim3(128, 3), 256, 0, stream>>>(q, k, v, Wtq, Wtk, Wtv, bq, bk, bv, Qb, Kb, Vtb);
  attn_kernel<<<dim3(64, 4), 256, 0, stream>>>(Qb, Kb, Vtb, out);
}

// Round 2
// 171.317 us; speedup vs baseline: 1.0923x; 1.0923x over previous
//
#include <hip/hip_runtime.h>
#include <hip/hip_bf16.h>
#include <cstdint>
#include <cmath>

// Shapes (hard-coded): B=4, S=4096, D=1024, DK=DV=128.
// ws layout: Qb[16384][128]bf16 @0 (4MB) | Kb @4MB | Vt[B][128][4096]bf16 @8MB
//            | Wtq bf16[128][1024] @12MB | Wtk | Wtv (ends 12.75MB)
//            | Po[nsplit][16384][128]f32 @13MB | ml[nsplit][16384][2]f32 after.

typedef __bf16 bf16x8 __attribute__((ext_vector_type(8)));
typedef float f32x4 __attribute__((ext_vector_type(4)));

__device__ __forceinline__ unsigned short f2bf(float f) {
  unsigned u = __float_as_uint(f);
  u += 0x7fffu + ((u >> 16) & 1u);   // RNE
  return (unsigned short)(u >> 16);
}

__device__ __forceinline__ bf16x8 ld_frag(const char* p) {
  uint4 u = *reinterpret_cast<const uint4*>(p);
  return __builtin_bit_cast(bf16x8, u);
}

// Q is pre-scaled by (1/sqrt(128)) * log2(e) so softmax uses exp2 directly.
#define QSCALE_LOG2E 0.12751744f

// ---------------- W transpose: [1024][128] f32 -> [128][1024] bf16 ----------
__global__ __launch_bounds__(256) void prep_wt_kernel(const float* __restrict__ W,
                                                      unsigned short* __restrict__ Wt) {
  __shared__ float tile[64][65];
  int kt = blockIdx.x, nt = blockIdx.y;   // (16, 2)
  int tid = threadIdx.x;
  int c = tid & 63;
  int r0 = (tid >> 6) * 16;
#pragma unroll
  for (int i = 0; i < 16; ++i) {
    int r = r0 + i;
    tile[r][c] = W[(size_t)(kt * 64 + r) * 128 + nt * 64 + c];
  }
  __syncthreads();
#pragma unroll
  for (int i = 0; i < 16; ++i) {
    int n = r0 + i;
    Wt[(size_t)(nt * 64 + n) * 1024 + kt * 64 + c] = f2bf(tile[c][n]);
  }
}

// ---------------- projections: X[16384][1024]f32 @ Wt -> bf16 outputs -------
__global__ __launch_bounds__(256) void proj_kernel(
    const float* __restrict__ qx, const float* __restrict__ kx, const float* __restrict__ vx,
    const unsigned short* __restrict__ Wtq, const unsigned short* __restrict__ Wtk,
    const unsigned short* __restrict__ Wtv,
    const float* __restrict__ bq, const float* __restrict__ bk, const float* __restrict__ bv,
    unsigned short* __restrict__ Qb, unsigned short* __restrict__ Kb,
    unsigned short* __restrict__ Vtb) {
  const int mode = blockIdx.y;  // 0=Q 1=K 2=V
  const float* x = (mode == 0) ? qx : (mode == 1) ? kx : vx;
  const unsigned short* Wt = (mode == 0) ? Wtq : (mode == 1) ? Wtk : Wtv;
  const float* bias = (mode == 0) ? bq : (mode == 1) ? bk : bv;

  __shared__ uint4 ldsA4[1024];  // 128 rows x 64 k bf16, swizzled
  __shared__ uint4 ldsW4[1024];  // 128 n-rows x 64 k bf16, swizzled
  char* ldsA = (char*)ldsA4;
  char* ldsW = (char*)ldsW4;

  const int tid = threadIdx.x;
  const int lane = tid & 63, wid = tid >> 6;
  const int l15 = lane & 15, hi = lane >> 4;
  const int wm = wid >> 1, wn = wid & 1;
  const long row0 = (long)blockIdx.x * 128;

  f32x4 acc[4][4];
#pragma unroll
  for (int i = 0; i < 4; ++i)
#pragma unroll
    for (int j = 0; j < 4; ++j) acc[i][j] = f32x4{0.f, 0.f, 0.f, 0.f};

  for (int kt = 0; kt < 16; ++kt) {
    const int k0 = kt * 64;
#pragma unroll
    for (int i = 0; i < 4; ++i) {
      int u = tid + 256 * i;          // 1024 units of 8 elems
      int row = u >> 3, c8 = u & 7;
      const float* src = x + (row0 + row) * 1024 + k0 + c8 * 8;
      float4 f0 = *reinterpret_cast<const float4*>(src);
      float4 f1 = *reinterpret_cast<const float4*>(src + 4);
      uint4 w;
      w.x = (unsigned)f2bf(f0.x) | ((unsigned)f2bf(f0.y) << 16);
      w.y = (unsigned)f2bf(f0.z) | ((unsigned)f2bf(f0.w) << 16);
      w.z = (unsigned)f2bf(f1.x) | ((unsigned)f2bf(f1.y) << 16);
      w.w = (unsigned)f2bf(f1.z) | ((unsigned)f2bf(f1.w) << 16);
      int off = (row * 128 + c8 * 16) ^ ((row & 7) << 4);
      *reinterpret_cast<uint4*>(ldsA + off) = w;
      const unsigned short* wsrc = Wt + (size_t)row * 1024 + k0 + c8 * 8;
      uint4 wv = *reinterpret_cast<const uint4*>(wsrc);
      *reinterpret_cast<uint4*>(ldsW + off) = wv;
    }
    __syncthreads();
#pragma unroll
    for (int kk = 0; kk < 2; ++kk) {
      bf16x8 af[4], bfv[4];
#pragma unroll
      for (int mi = 0; mi < 4; ++mi) {
        int row = wm * 64 + mi * 16 + l15;
        af[mi] = ld_frag(ldsA + ((row * 128 + kk * 64 + hi * 16) ^ ((row & 7) << 4)));
      }
#pragma unroll
      for (int ni = 0; ni < 4; ++ni) {
        int row = wn * 64 + ni * 16 + l15;
        bfv[ni] = ld_frag(ldsW + ((row * 128 + kk * 64 + hi * 16) ^ ((row & 7) << 4)));
      }
#pragma unroll
      for (int mi = 0; mi < 4; ++mi)
#pragma unroll
        for (int ni = 0; ni < 4; ++ni)
          acc[mi][ni] = __builtin_amdgcn_mfma_f32_16x16x32_bf16(af[mi], bfv[ni], acc[mi][ni], 0, 0, 0);
    }
    __syncthreads();
  }

#pragma unroll
  for (int ni = 0; ni < 4; ++ni) {
    int n = wn * 64 + ni * 16 + l15;
    float bv_ = bias[n];
#pragma unroll
    for (int mi = 0; mi < 4; ++mi) {
      long m = row0 + wm * 64 + mi * 16 + hi * 4;
      f32x4 a = acc[mi][ni];
      if (mode == 2) {
        int bb = (int)(m >> 12);
        int s = (int)(m & 4095);
        ushort4 pk;
        pk.x = f2bf(a.x + bv_); pk.y = f2bf(a.y + bv_);
        pk.z = f2bf(a.z + bv_); pk.w = f2bf(a.w + bv_);
        *reinterpret_cast<ushort4*>(Vtb + ((size_t)(bb * 128 + n)) * 4096 + s) = pk;
      } else {
        const float sc = (mode == 0) ? QSCALE_LOG2E : 1.0f;
        unsigned short* outp = (mode == 0) ? Qb : Kb;
        outp[(m + 0) * 128 + n] = f2bf((a.x + bv_) * sc);
        outp[(m + 1) * 128 + n] = f2bf((a.y + bv_) * sc);
        outp[(m + 2) * 128 + n] = f2bf((a.z + bv_) * sc);
        outp[(m + 3) * 128 + n] = f2bf((a.w + bv_) * sc);
      }
    }
  }
}

// ---------------- flash attention (KV-split, partial outputs) ---------------
__global__ __launch_bounds__(256) void attn_kernel(
    const unsigned short* __restrict__ Qb, const unsigned short* __restrict__ Kb,
    const unsigned short* __restrict__ Vtb, float* __restrict__ Po,
    float* __restrict__ ml, int tps) {
  __shared__ uint4 ldsK4[1024];  // 64 kv-rows x 128 d bf16, swizzled
  __shared__ uint4 ldsV4[1024];  // 128 dv-rows x 64 k bf16, swizzled
  __shared__ uint4 ldsP4[512];   // per-wave 16 x 64 bf16, swizzled
  char* ldsK = (char*)ldsK4;
  char* ldsV = (char*)ldsV4;
  char* ldsP = (char*)ldsP4;

  const int tid = threadIdx.x;
  const int lane = tid & 63, wid = tid >> 6;
  const int l15 = lane & 15, hi = lane >> 4;
  const int split = blockIdx.y;
  const int b = blockIdx.z;
  const int q0 = blockIdx.x * 64 + wid * 16;

  // hoist Q fragments (A-operand: 16 rows x 128 d)
  bf16x8 qf[4];
  {
    const unsigned short* qp = Qb + ((size_t)(b * 4096) + q0 + l15) * 128 + hi * 8;
#pragma unroll
    for (int kd = 0; kd < 4; ++kd)
      qf[kd] = __builtin_bit_cast(bf16x8, *reinterpret_cast<const uint4*>(qp + kd * 32));
  }

  f32x4 oacc[8];
#pragma unroll
  for (int d = 0; d < 8; ++d) oacc[d] = f32x4{0.f, 0.f, 0.f, 0.f};
  float mrun[4], lrun[4];
#pragma unroll
  for (int r = 0; r < 4; ++r) { mrun[r] = -INFINITY; lrun[r] = 0.f; }

  char* pbase = ldsP + wid * 2048;
  const int t0 = split * tps, t1 = t0 + tps;

  for (int t = t0; t < t1; ++t) {
    const int kv0 = t * 64;
    // stage K tile [64][128] bf16
    const char* kg = (const char*)Kb + ((size_t)(b * 4096) + kv0) * 256;
#pragma unroll
    for (int i = 0; i < 4; ++i) {
      int u = tid + 256 * i;
      int row = u >> 4, c = u & 15;
      uint4 val = *reinterpret_cast<const uint4*>(kg + row * 256 + c * 16);
      *reinterpret_cast<uint4*>(ldsK + ((row * 256 + c * 16) ^ ((row & 7) << 4))) = val;
    }
    // stage Vt tile [128 dv][64 k] bf16
    const char* vg = (const char*)Vtb + (size_t)b * 128 * 4096 * 2 + (size_t)kv0 * 2;
#pragma unroll
    for (int i = 0; i < 4; ++i) {
      int u = tid + 256 * i;
      int dv = u >> 3, c = u & 7;
      uint4 val = *reinterpret_cast<const uint4*>(vg + (size_t)dv * 8192 + c * 16);
      *reinterpret_cast<uint4*>(ldsV + ((dv * 128 + c * 16) ^ ((dv & 7) << 4))) = val;
    }
    __syncthreads();

    // QK^T: sc[j0] holds D rows = q (hi*4+r), col = kv (j0*16 + l15)
    f32x4 sc[4];
#pragma unroll
    for (int j0 = 0; j0 < 4; ++j0) sc[j0] = f32x4{0.f, 0.f, 0.f, 0.f};
    __builtin_amdgcn_s_setprio(1);
#pragma unroll
    for (int j0 = 0; j0 < 4; ++j0) {
      int row = j0 * 16 + l15;
#pragma unroll
      for (int kd = 0; kd < 4; ++kd) {
        bf16x8 kf = ld_frag(ldsK + ((row * 256 + kd * 64 + hi * 16) ^ ((row & 7) << 4)));
        sc[j0] = __builtin_amdgcn_mfma_f32_16x16x32_bf16(qf[kd], kf, sc[j0], 0, 0, 0);
      }
    }
    __builtin_amdgcn_s_setprio(0);

    // online softmax (scores already in log2 domain)
    float mt[4];
#pragma unroll
    for (int r = 0; r < 4; ++r)
      mt[r] = fmaxf(fmaxf(sc[0][r], sc[1][r]), fmaxf(sc[2][r], sc[3][r]));
#pragma unroll
    for (int r = 0; r < 4; ++r) {
      mt[r] = fmaxf(mt[r], __shfl_xor(mt[r], 1));
      mt[r] = fmaxf(mt[r], __shfl_xor(mt[r], 2));
      mt[r] = fmaxf(mt[r], __shfl_xor(mt[r], 4));
      mt[r] = fmaxf(mt[r], __shfl_xor(mt[r], 8));
    }
    const bool nogrow = __all((mt[0] <= mrun[0]) & (mt[1] <= mrun[1]) &
                              (mt[2] <= mrun[2]) & (mt[3] <= mrun[3]));
    float mnew[4], psum[4];
    if (nogrow) {
#pragma unroll
      for (int r = 0; r < 4; ++r) { mnew[r] = mrun[r]; psum[r] = 0.f; }
    } else {
      float scl[4];
#pragma unroll
      for (int r = 0; r < 4; ++r) {
        mnew[r] = fmaxf(mrun[r], mt[r]);
        scl[r] = exp2f(mrun[r] - mnew[r]);
        mrun[r] = mnew[r];
        psum[r] = 0.f;
        lrun[r] *= scl[r];
      }
#pragma unroll
      for (int d = 0; d < 8; ++d) {
        oacc[d][0] *= scl[0]; oacc[d][1] *= scl[1];
        oacc[d][2] *= scl[2]; oacc[d][3] *= scl[3];
      }
    }
    // P = exp2(sc - m), write bf16 to per-wave LDS in A-layout source form
#pragma unroll
    for (int j0 = 0; j0 < 4; ++j0) {
#pragma unroll
      for (int r = 0; r < 4; ++r) {
        float p = exp2f(sc[j0][r] - mnew[r]);
        psum[r] += p;
        int row = hi * 4 + r;
        int off = (row * 128 + (j0 * 16 + l15) * 2) ^ ((row & 7) << 4);
        *reinterpret_cast<unsigned short*>(pbase + off) = f2bf(p);
      }
    }
#pragma unroll
    for (int r = 0; r < 4; ++r) {
      psum[r] += __shfl_xor(psum[r], 1);
      psum[r] += __shfl_xor(psum[r], 2);
      psum[r] += __shfl_xor(psum[r], 4);
      psum[r] += __shfl_xor(psum[r], 8);
      lrun[r] += psum[r];
    }

    asm volatile("s_waitcnt lgkmcnt(0)" ::: "memory");  // P writes -> P reads (wave-local)

    // PV: A = P (16x64), B = V (64 x 128dv) from Vt rows
    __builtin_amdgcn_s_setprio(1);
#pragma unroll
    for (int kk = 0; kk < 2; ++kk) {
      bf16x8 pf = ld_frag(pbase + ((l15 * 128 + kk * 64 + hi * 16) ^ ((l15 & 7) << 4)));
#pragma unroll
      for (int d = 0; d < 8; ++d) {
        int vrow = d * 16 + l15;
        bf16x8 vf = ld_frag(ldsV + ((vrow * 128 + kk * 64 + hi * 16) ^ ((vrow & 7) << 4)));
        oacc[d] = __builtin_amdgcn_mfma_f32_16x16x32_bf16(pf, vf, oacc[d], 0, 0, 0);
      }
    }
    __builtin_amdgcn_s_setprio(0);
    __syncthreads();
  }

  // epilogue: store UNNORMALIZED partial O + (m, l)
  float* po = Po + ((size_t)split << 21);
#pragma unroll
  for (int d = 0; d < 8; ++d) {
#pragma unroll
    for (int r = 0; r < 4; ++r) {
      size_t grow = (size_t)(b * 4096) + q0 + hi * 4 + r;
      po[grow * 128 + d * 16 + l15] = oacc[d][r];
    }
  }
  if (l15 == 0) {
    float* mlp = ml + (size_t)split * 32768;
#pragma unroll
    for (int r = 0; r < 4; ++r) {
      size_t grow = (size_t)(b * 4096) + q0 + hi * 4 + r;
      mlp[grow * 2 + 0] = mrun[r];
      mlp[grow * 2 + 1] = lrun[r];
    }
  }
}

// ---------------- combine partials ------------------------------------------
template <int NS>
__global__ __launch_bounds__(256) void combine_kernel(const float* __restrict__ Po,
                                                      const float* __restrict__ ml,
                                                      float* __restrict__ out) {
  int idx = blockIdx.x * 256 + threadIdx.x;  // 16384*32 float4-units
  int grow = idx >> 5;
  int c4 = (idx & 31) * 4;
  float m[NS], l[NS];
  float M = -INFINITY;
#pragma unroll
  for (int s = 0; s < NS; ++s) {
    m[s] = ml[(size_t)s * 32768 + grow * 2 + 0];
    l[s] = ml[(size_t)s * 32768 + grow * 2 + 1];
    M = fmaxf(M, m[s]);
  }
  float L = 0.f, w[NS];
#pragma unroll
  for (int s = 0; s < NS; ++s) {
    w[s] = exp2f(m[s] - M);   // log2 domain
    L += l[s] * w[s];
  }
  float invL = 1.0f / L;
  float4 acc = {0.f, 0.f, 0.f, 0.f};
#pragma unroll
  for (int s = 0; s < NS; ++s) {
    float4 p = *reinterpret_cast<const float4*>(Po + ((size_t)s << 21) + (size_t)grow * 128 + c4);
    acc.x += p.x * w[s]; acc.y += p.y * w[s];
    acc.z += p.z * w[s]; acc.w += p.w * w[s];
  }
  acc.x *= invL; acc.y *= invL; acc.z *= invL; acc.w *= invL;
  *reinterpret_cast<float4*>(out + (size_t)grow * 128 + c4) = acc;
}

extern "C" void kernel_launch(void* const* d_in, const int* in_sizes, int n_in,
                              void* d_out, int out_size, void* d_ws, size_t ws_size,
                              hipStream_t stream) {
  const float* q  = (const float*)d_in[0];
  const float* k  = (const float*)d_in[1];
  const float* v  = (const float*)d_in[2];
  const float* Wq = (const float*)d_in[3];
  const float* bq = (const float*)d_in[4];
  const float* Wk = (const float*)d_in[5];
  const float* bk = (const float*)d_in[6];
  const float* Wv = (const float*)d_in[7];
  const float* bv = (const float*)d_in[8];
  float* out = (float*)d_out;

  char* ws = (char*)d_ws;
  unsigned short* Qb  = (unsigned short*)(ws);
  unsigned short* Kb  = (unsigned short*)(ws + (4u << 20));
  unsigned short* Vtb = (unsigned short*)(ws + (8u << 20));
  unsigned short* Wtq = (unsigned short*)(ws + (12u << 20));
  unsigned short* Wtk = (unsigned short*)(ws + (12u << 20) + (256u << 10));
  unsigned short* Wtv = (unsigned short*)(ws + (12u << 20) + (512u << 10));

  const size_t base = (size_t)13 << 20;
  const size_t per = ((size_t)8 << 20) + ((size_t)128 << 10);
  int nsplit = 1;
  if (ws_size >= base + 4 * per) nsplit = 4;
  else if (ws_size >= base + 2 * per) nsplit = 2;
  float* Po = (float*)(ws + base);
  float* ml = (float*)(ws + base + (size_t)nsplit * ((size_t)8 << 20));

  prep_wt_kernel<<<dim3(16, 2), 256, 0, stream>>>(Wq, Wtq);
  prep_wt_kernel<<<dim3(16, 2), 256, 0, stream>>>(Wk, Wtk);
  prep_wt_kernel<<<dim3(16, 2), 256, 0, stream>>>(Wv, Wtv);
  proj_kernel<<<dim3(128, 3), 256, 0, stream>>>(q, k, v, Wtq, Wtk, Wtv, bq, bk, bv, Qb, Kb, Vtb);
  attn_kernel<<<dim3(64, nsplit, 4), 256, 0, stream>>>(Qb, Kb, Vtb, Po, ml, 64 / nsplit);
  if (nsplit == 4)      combine_kernel<4><<<2048, 256, 0, stream>>>(Po, ml, out);
  else if (nsplit == 2) combine_kernel<2><<<2048, 256, 0, stream>>>(Po, ml, out);
  else                  combine_kernel<1><<<2048, 256, 0, stream>>>(Po, ml, out);
}

// Round 3
// 108.202 us; speedup vs baseline: 1.7294x; 1.5833x over previous
//
#include <hip/hip_runtime.h>
#include <hip/hip_bf16.h>
#include <cstdint>
#include <cmath>

// Shapes (hard-coded): B=4, S=4096, D=1024, DK=DV=128.
// ws layout: Qb[16384][128]bf16 @0 (4MB) | Kb @4MB | Vt[B][128][4096]bf16 @8MB
//            | Wtq bf16[128][1024] @12MB | Wtk | Wtv (ends 12.75MB)
//            | Po[nsplit][16384][128]f32 @13MB | ml[nsplit][16384][2]f32 after.

typedef __bf16 bf16x8 __attribute__((ext_vector_type(8)));
typedef float f32x4 __attribute__((ext_vector_type(4)));
typedef float f32x16 __attribute__((ext_vector_type(16)));

__device__ __forceinline__ unsigned short f2bf(float f) {
  unsigned u = __float_as_uint(f);
  u += 0x7fffu + ((u >> 16) & 1u);   // RNE
  return (unsigned short)(u >> 16);
}

__device__ __forceinline__ bf16x8 ld_frag(const char* p) {
  uint4 u = *reinterpret_cast<const uint4*>(p);
  return __builtin_bit_cast(bf16x8, u);
}

__device__ __forceinline__ unsigned cvtpk_bf16(float lo, float hi) {
  unsigned r;
  asm("v_cvt_pk_bf16_f32 %0, %1, %2" : "=v"(r) : "v"(lo), "v"(hi));
  return r;
}

__device__ __forceinline__ void pl32swap(unsigned &a, unsigned &b) {
  asm("v_permlane32_swap_b32 %0, %1" : "+v"(a), "+v"(b));
}

__device__ __forceinline__ bf16x8 mk_frag(unsigned w0, unsigned w1, unsigned w2, unsigned w3) {
  uint4 u{w0, w1, w2, w3};
  return __builtin_bit_cast(bf16x8, u);
}

// Q is pre-scaled by (1/sqrt(128)) * log2(e) so softmax uses exp2 directly.
#define QSCALE_LOG2E 0.12751744f

// ---------------- W transpose: [1024][128] f32 -> [128][1024] bf16 ----------
__global__ __launch_bounds__(256) void prep_wt_kernel(const float* __restrict__ W,
                                                      unsigned short* __restrict__ Wt) {
  __shared__ float tile[64][65];
  int kt = blockIdx.x, nt = blockIdx.y;   // (16, 2)
  int tid = threadIdx.x;
  int c = tid & 63;
  int r0 = (tid >> 6) * 16;
#pragma unroll
  for (int i = 0; i < 16; ++i) {
    int r = r0 + i;
    tile[r][c] = W[(size_t)(kt * 64 + r) * 128 + nt * 64 + c];
  }
  __syncthreads();
#pragma unroll
  for (int i = 0; i < 16; ++i) {
    int n = r0 + i;
    Wt[(size_t)(nt * 64 + n) * 1024 + kt * 64 + c] = f2bf(tile[c][n]);
  }
}

// ---------------- projections: X[16384][1024]f32 @ Wt -> bf16 outputs -------
__global__ __launch_bounds__(256) void proj_kernel(
    const float* __restrict__ qx, const float* __restrict__ kx, const float* __restrict__ vx,
    const unsigned short* __restrict__ Wtq, const unsigned short* __restrict__ Wtk,
    const unsigned short* __restrict__ Wtv,
    const float* __restrict__ bq, const float* __restrict__ bk, const float* __restrict__ bv,
    unsigned short* __restrict__ Qb, unsigned short* __restrict__ Kb,
    unsigned short* __restrict__ Vtb) {
  const int mode = blockIdx.y;  // 0=Q 1=K 2=V
  const float* x = (mode == 0) ? qx : (mode == 1) ? kx : vx;
  const unsigned short* Wt = (mode == 0) ? Wtq : (mode == 1) ? Wtk : Wtv;
  const float* bias = (mode == 0) ? bq : (mode == 1) ? bk : bv;

  __shared__ uint4 ldsA4[1024];  // 128 rows x 64 k bf16, swizzled
  __shared__ uint4 ldsW4[1024];  // 128 n-rows x 64 k bf16, swizzled
  char* ldsA = (char*)ldsA4;
  char* ldsW = (char*)ldsW4;

  const int tid = threadIdx.x;
  const int lane = tid & 63, wid = tid >> 6;
  const int l15 = lane & 15, hi = lane >> 4;
  const int wm = wid >> 1, wn = wid & 1;
  const long row0 = (long)blockIdx.x * 128;

  f32x4 acc[4][4];
#pragma unroll
  for (int i = 0; i < 4; ++i)
#pragma unroll
    for (int j = 0; j < 4; ++j) acc[i][j] = f32x4{0.f, 0.f, 0.f, 0.f};

  for (int kt = 0; kt < 16; ++kt) {
    const int k0 = kt * 64;
#pragma unroll
    for (int i = 0; i < 4; ++i) {
      int u = tid + 256 * i;          // 1024 units of 8 elems
      int row = u >> 3, c8 = u & 7;
      const float* src = x + (row0 + row) * 1024 + k0 + c8 * 8;
      float4 f0 = *reinterpret_cast<const float4*>(src);
      float4 f1 = *reinterpret_cast<const float4*>(src + 4);
      uint4 w;
      w.x = (unsigned)f2bf(f0.x) | ((unsigned)f2bf(f0.y) << 16);
      w.y = (unsigned)f2bf(f0.z) | ((unsigned)f2bf(f0.w) << 16);
      w.z = (unsigned)f2bf(f1.x) | ((unsigned)f2bf(f1.y) << 16);
      w.w = (unsigned)f2bf(f1.z) | ((unsigned)f2bf(f1.w) << 16);
      int off = (row * 128 + c8 * 16) ^ ((row & 7) << 4);
      *reinterpret_cast<uint4*>(ldsA + off) = w;
      const unsigned short* wsrc = Wt + (size_t)row * 1024 + k0 + c8 * 8;
      uint4 wv = *reinterpret_cast<const uint4*>(wsrc);
      *reinterpret_cast<uint4*>(ldsW + off) = wv;
    }
    __syncthreads();
#pragma unroll
    for (int kk = 0; kk < 2; ++kk) {
      bf16x8 af[4], bfv[4];
#pragma unroll
      for (int mi = 0; mi < 4; ++mi) {
        int row = wm * 64 + mi * 16 + l15;
        af[mi] = ld_frag(ldsA + ((row * 128 + kk * 64 + hi * 16) ^ ((row & 7) << 4)));
      }
#pragma unroll
      for (int ni = 0; ni < 4; ++ni) {
        int row = wn * 64 + ni * 16 + l15;
        bfv[ni] = ld_frag(ldsW + ((row * 128 + kk * 64 + hi * 16) ^ ((row & 7) << 4)));
      }
#pragma unroll
      for (int mi = 0; mi < 4; ++mi)
#pragma unroll
        for (int ni = 0; ni < 4; ++ni)
          acc[mi][ni] = __builtin_amdgcn_mfma_f32_16x16x32_bf16(af[mi], bfv[ni], acc[mi][ni], 0, 0, 0);
    }
    __syncthreads();
  }

#pragma unroll
  for (int ni = 0; ni < 4; ++ni) {
    int n = wn * 64 + ni * 16 + l15;
    float bv_ = bias[n];
#pragma unroll
    for (int mi = 0; mi < 4; ++mi) {
      long m = row0 + wm * 64 + mi * 16 + hi * 4;
      f32x4 a = acc[mi][ni];
      if (mode == 2) {
        int bb = (int)(m >> 12);
        int s = (int)(m & 4095);
        ushort4 pk;
        pk.x = f2bf(a.x + bv_); pk.y = f2bf(a.y + bv_);
        pk.z = f2bf(a.z + bv_); pk.w = f2bf(a.w + bv_);
        *reinterpret_cast<ushort4*>(Vtb + ((size_t)(bb * 128 + n)) * 4096 + s) = pk;
      } else {
        const float sc = (mode == 0) ? QSCALE_LOG2E : 1.0f;
        unsigned short* outp = (mode == 0) ? Qb : Kb;
        outp[(m + 0) * 128 + n] = f2bf((a.x + bv_) * sc);
        outp[(m + 1) * 128 + n] = f2bf((a.y + bv_) * sc);
        outp[(m + 2) * 128 + n] = f2bf((a.z + bv_) * sc);
        outp[(m + 3) * 128 + n] = f2bf((a.w + bv_) * sc);
      }
    }
  }
}

// ---------------- flash attention (32x32 swapped-operand, KV-split) ---------
// Block: 4 waves x 32 q-rows. Per lane: q = lane&31 for ALL phases.
// QK^T: S^T = mfma(A=K[kv][d], B=Q[d][q]) -> C[kv][q], col=lane&31=q.
// PV:   O^T = mfma(A=Vt[dv][kv], B=P^T[kv][q]) -> C[dv][q], col=lane&31=q.
__global__ __launch_bounds__(256, 2) void attn_kernel(
    const unsigned short* __restrict__ Qb, const unsigned short* __restrict__ Kb,
    const unsigned short* __restrict__ Vtb, float* __restrict__ Po,
    float* __restrict__ ml, int tps) {
  __shared__ uint4 ldsK4[1024];  // 64 kv-rows x 128 d bf16, swizzled (16KB)
  __shared__ uint4 ldsV4[1024];  // 128 dv-rows x 64 k bf16, swizzled (16KB)
  char* ldsK = (char*)ldsK4;
  char* ldsV = (char*)ldsV4;

  const int tid = threadIdx.x;
  const int lane = tid & 63, wid = tid >> 6;
  const int l31 = lane & 31, hi = lane >> 5;
  const int split = blockIdx.y;
  const int b = blockIdx.z;
  const int qbase = blockIdx.x * 128 + wid * 32;  // within batch
  const size_t growq = (size_t)b * 4096 + qbase + l31;

  // Q fragments (B-operand): qf[kt] elem e <-> d = kt*16 + hi*8 + e
  bf16x8 qf[8];
  {
    const unsigned short* qp = Qb + growq * 128 + hi * 8;
#pragma unroll
    for (int kt = 0; kt < 8; ++kt)
      qf[kt] = __builtin_bit_cast(bf16x8, *reinterpret_cast<const uint4*>(qp + kt * 16));
  }

  f32x16 oacc[4];
#pragma unroll
  for (int d = 0; d < 4; ++d)
#pragma unroll
    for (int j = 0; j < 16; ++j) oacc[d][j] = 0.f;
  float mrun = -INFINITY, lrun = 0.f;

  const int t0 = split * tps, t1 = t0 + tps;

  for (int t = t0; t < t1; ++t) {
    const int kv0 = t * 64;
    // stage K tile [64][128] bf16 (swizzled)
    const char* kg = (const char*)Kb + ((size_t)(b * 4096) + kv0) * 256;
#pragma unroll
    for (int i = 0; i < 4; ++i) {
      int u = tid + 256 * i;
      int row = u >> 4, c = u & 15;
      uint4 val = *reinterpret_cast<const uint4*>(kg + row * 256 + c * 16);
      *reinterpret_cast<uint4*>(ldsK + ((row * 256 + c * 16) ^ ((row & 7) << 4))) = val;
    }
    // stage Vt tile [128 dv][64 k] bf16 (swizzled)
    const char* vg = (const char*)Vtb + (size_t)b * 128 * 4096 * 2 + (size_t)kv0 * 2;
#pragma unroll
    for (int i = 0; i < 4; ++i) {
      int u = tid + 256 * i;
      int dv = u >> 3, c = u & 7;
      uint4 val = *reinterpret_cast<const uint4*>(vg + (size_t)dv * 8192 + c * 16);
      *reinterpret_cast<uint4*>(ldsV + ((dv * 128 + c * 16) ^ ((dv & 7) << 4))) = val;
    }
    __syncthreads();

    // ---- QK^T (swapped): sc_c[reg] = S[kv = (reg&3)+8*(reg>>2)+4*hi + 32c][q = l31]
    f32x16 sc0, sc1;
#pragma unroll
    for (int j = 0; j < 16; ++j) { sc0[j] = 0.f; sc1[j] = 0.f; }
    __builtin_amdgcn_s_setprio(1);
#pragma unroll
    for (int kvb = 0; kvb < 2; ++kvb) {
      int row = kvb * 32 + l31;
      int rowoff = row * 256, swz = (row & 7) << 4;
#pragma unroll
      for (int kt = 0; kt < 8; ++kt) {
        bf16x8 kf = ld_frag(ldsK + ((rowoff + kt * 32 + hi * 16) ^ swz));
        if (kvb == 0) sc0 = __builtin_amdgcn_mfma_f32_32x32x16_bf16(kf, qf[kt], sc0, 0, 0, 0);
        else          sc1 = __builtin_amdgcn_mfma_f32_32x32x16_bf16(kf, qf[kt], sc1, 0, 0, 0);
      }
    }
    __builtin_amdgcn_s_setprio(0);

    // ---- online softmax, fully per-lane (q = l31; partner lane = l31+32*!hi)
    float tmx[16];
#pragma unroll
    for (int i = 0; i < 16; ++i) tmx[i] = fmaxf(sc0[i], sc1[i]);
#pragma unroll
    for (int s = 8; s > 0; s >>= 1)
#pragma unroll
      for (int i = 0; i < s; ++i) tmx[i] = fmaxf(tmx[i], tmx[i + s]);
    float mt = tmx[0];
    mt = fmaxf(mt, __shfl_xor(mt, 32));

    // defer-max (T13): only rescale when tile max grows past threshold
    if (!__all(mt - mrun <= 8.0f)) {
      float mnew = fmaxf(mrun, mt);
      float scl = exp2f(mrun - mnew);
      mrun = mnew;
      lrun *= scl;
#pragma unroll
      for (int d = 0; d < 4; ++d)
#pragma unroll
        for (int j = 0; j < 16; ++j) oacc[d][j] *= scl;
    }

    // P = exp2(S - m) in-register
#pragma unroll
    for (int i = 0; i < 16; ++i) {
      sc0[i] = exp2f(sc0[i] - mrun);
      sc1[i] = exp2f(sc1[i] - mrun);
    }
    float ts[16];
#pragma unroll
    for (int i = 0; i < 16; ++i) ts[i] = sc0[i] + sc1[i];
#pragma unroll
    for (int s = 8; s > 0; s >>= 1)
#pragma unroll
      for (int i = 0; i < s; ++i) ts[i] += ts[i + s];
    float psum = ts[0];
    psum += __shfl_xor(psum, 32);
    lrun += psum;

    // ---- P -> bf16 A/B-fragments via cvt_pk + permlane32_swap (T12)
    // pa[tt] elem e <-> kv = tt*16 + hi*8 + e  (B-operand layout for PV)
    bf16x8 pa[4];
#pragma unroll
    for (int c = 0; c < 2; ++c) {
      const f32x16& p = c ? sc1 : sc0;
#pragma unroll
      for (int g = 0; g < 2; ++g) {
        const int base = g * 8;
        unsigned a0 = cvtpk_bf16(p[base + 0], p[base + 1]);
        unsigned b0 = cvtpk_bf16(p[base + 4], p[base + 5]);
        pl32swap(a0, b0);
        unsigned a1 = cvtpk_bf16(p[base + 2], p[base + 3]);
        unsigned b1 = cvtpk_bf16(p[base + 6], p[base + 7]);
        pl32swap(a1, b1);
        pa[c * 2 + g] = mk_frag(a0, a1, b0, b1);
      }
    }

    // ---- PV (swapped): oacc[dvb] += mfma(A=Vt rows, B=P^T)
    __builtin_amdgcn_s_setprio(1);
#pragma unroll
    for (int dvb = 0; dvb < 4; ++dvb) {
      int vrow = dvb * 32 + l31;
      int voff = vrow * 128, vswz = (vrow & 7) << 4;
#pragma unroll
      for (int tt = 0; tt < 4; ++tt) {
        bf16x8 vf = ld_frag(ldsV + ((voff + tt * 32 + hi * 16) ^ vswz));
        oacc[dvb] = __builtin_amdgcn_mfma_f32_32x32x16_bf16(vf, pa[tt], oacc[dvb], 0, 0, 0);
      }
    }
    __builtin_amdgcn_s_setprio(0);
    __syncthreads();
  }

  // ---- epilogue: ml + O^T -> O via per-wave LDS transpose, coalesced stores
  if (hi == 0) {
    float* mlp = ml + (size_t)split * 32768 + growq * 2;
    mlp[0] = mrun; mlp[1] = lrun;
  }

  float* po = Po + ((size_t)split << 21) + ((size_t)b * 4096 + qbase) * 128;
  char* tbase = ldsK + wid * 4096;  // 32q x 32dv f32 = 4KB per wave
  for (int dvb = 0; dvb < 4; ++dvb) {
    // write transposed: [q = l31][dv_local = 8g+4hi + j]
#pragma unroll
    for (int g = 0; g < 4; ++g) {
      float4 w4{oacc[dvb][g * 4 + 0], oacc[dvb][g * 4 + 1],
                oacc[dvb][g * 4 + 2], oacc[dvb][g * 4 + 3]};
      int off = (l31 * 128 + g * 32 + hi * 16) ^ ((l31 & 7) << 4);
      *reinterpret_cast<float4*>(tbase + off) = w4;
    }
    asm volatile("s_waitcnt lgkmcnt(0)" ::: "memory");
    __builtin_amdgcn_sched_barrier(0);
#pragma unroll
    for (int qq = 0; qq < 4; ++qq) {
      int q = qq * 8 + (lane >> 3);
      int off = (q * 128 + (lane & 7) * 16) ^ ((q & 7) << 4);
      float4 r4 = *reinterpret_cast<const float4*>(tbase + off);
      *reinterpret_cast<float4*>(po + (size_t)q * 128 + dvb * 32 + (lane & 7) * 4) = r4;
    }
    asm volatile("s_waitcnt lgkmcnt(0)" ::: "memory");
    __builtin_amdgcn_sched_barrier(0);
  }
}

// ---------------- combine partials ------------------------------------------
template <int NS>
__global__ __launch_bounds__(256) void combine_kernel(const float* __restrict__ Po,
                                                      const float* __restrict__ ml,
                                                      float* __restrict__ out) {
  int idx = blockIdx.x * 256 + threadIdx.x;  // 16384*32 float4-units
  int grow = idx >> 5;
  int c4 = (idx & 31) * 4;
  float m[NS], l[NS];
  float M = -INFINITY;
#pragma unroll
  for (int s = 0; s < NS; ++s) {
    m[s] = ml[(size_t)s * 32768 + grow * 2 + 0];
    l[s] = ml[(size_t)s * 32768 + grow * 2 + 1];
    M = fmaxf(M, m[s]);
  }
  float L = 0.f, w[NS];
#pragma unroll
  for (int s = 0; s < NS; ++s) {
    w[s] = exp2f(m[s] - M);   // log2 domain
    L += l[s] * w[s];
  }
  float invL = 1.0f / L;
  float4 acc = {0.f, 0.f, 0.f, 0.f};
#pragma unroll
  for (int s = 0; s < NS; ++s) {
    float4 p = *reinterpret_cast<const float4*>(Po + ((size_t)s << 21) + (size_t)grow * 128 + c4);
    acc.x += p.x * w[s]; acc.y += p.y * w[s];
    acc.z += p.z * w[s]; acc.w += p.w * w[s];
  }
  acc.x *= invL; acc.y *= invL; acc.z *= invL; acc.w *= invL;
  *reinterpret_cast<float4*>(out + (size_t)grow * 128 + c4) = acc;
}

extern "C" void kernel_launch(void* const* d_in, const int* in_sizes, int n_in,
                              void* d_out, int out_size, void* d_ws, size_t ws_size,
                              hipStream_t stream) {
  const float* q  = (const float*)d_in[0];
  const float* k  = (const float*)d_in[1];
  const float* v  = (const float*)d_in[2];
  const float* Wq = (const float*)d_in[3];
  const float* bq = (const float*)d_in[4];
  const float* Wk = (const float*)d_in[5];
  const float* bk = (const float*)d_in[6];
  const float* Wv = (const float*)d_in[7];
  const float* bv = (const float*)d_in[8];
  float* out = (float*)d_out;

  char* ws = (char*)d_ws;
  unsigned short* Qb  = (unsigned short*)(ws);
  unsigned short* Kb  = (unsigned short*)(ws + (4u << 20));
  unsigned short* Vtb = (unsigned short*)(ws + (8u << 20));
  unsigned short* Wtq = (unsigned short*)(ws + (12u << 20));
  unsigned short* Wtk = (unsigned short*)(ws + (12u << 20) + (256u << 10));
  unsigned short* Wtv = (unsigned short*)(ws + (12u << 20) + (512u << 10));

  const size_t base = (size_t)13 << 20;
  const size_t per = ((size_t)8 << 20) + ((size_t)128 << 10);
  int nsplit = 1;
  if (ws_size >= base + 4 * per) nsplit = 4;
  else if (ws_size >= base + 2 * per) nsplit = 2;
  float* Po = (float*)(ws + base);
  float* ml = (float*)(ws + base + (size_t)nsplit * ((size_t)8 << 20));

  prep_wt_kernel<<<dim3(16, 2), 256, 0, stream>>>(Wq, Wtq);
  prep_wt_kernel<<<dim3(16, 2), 256, 0, stream>>>(Wk, Wtk);
  prep_wt_kernel<<<dim3(16, 2), 256, 0, stream>>>(Wv, Wtv);
  proj_kernel<<<dim3(128, 3), 256, 0, stream>>>(q, k, v, Wtq, Wtk, Wtv, bq, bk, bv, Qb, Kb, Vtb);
  attn_kernel<<<dim3(32, nsplit, 4), 256, 0, stream>>>(Qb, Kb, Vtb, Po, ml, 64 / nsplit);
  if (nsplit == 4)      combine_kernel<4><<<2048, 256, 0, stream>>>(Po, ml, out);
  else if (nsplit == 2) combine_kernel<2><<<2048, 256, 0, stream>>>(Po, ml, out);
  else                  combine_kernel<1><<<2048, 256, 0, stream>>>(Po, ml, out);
}